// Round 10
// baseline (423.314 us; speedup 1.0000x reference)
//
#include <hip/hip_runtime.h>

// Neighbor aggregation: out[b, dst] += w * H[b, src], H rows = 256 fp32.
// R10 = R9 + prep fix: INTERLEAVED fused prep (every thread streams the
// H->fp16 convert and interleaves one edge-scatter per iteration) instead of
// static block role-split. Role-split starved cvt to 44% of issue rate
// (prep 165us ~= 410MB at 44% BW); interleave gives cvt 100% of waves and
// hides scatter's atomic latency under the stream.
// Aggregate (unchanged, at its compulsory-miss wall ~220us): one wave per
// (b,node), cap-32 one-line segments, 8-deep gather pipeline, nt stores.

constexpr int ROW = 256;        // HS*HS
constexpr int CAP = 32;         // records per (b,dst) segment = one 128B line
constexpr int OVFCAP = 262144;

typedef _Float16 half4 __attribute__((ext_vector_type(4)));
typedef float fvec4 __attribute__((ext_vector_type(4)));

static __device__ inline float h2f_bits(unsigned short u) {
    _Float16 h; __builtin_memcpy(&h, &u, 2); return (float)h;
}

__global__ void k_init(const int* __restrict__ nidx, int* __restrict__ inv,
                       int* __restrict__ zbuf, int nz, int N) {
    int i = blockIdx.x * blockDim.x + threadIdx.x;
    if (i < N) inv[nidx[i]] = i;
    if (i < nz) zbuf[i] = 0;
}

// Interleaved fused prep: per grid-stride iteration, one scatter edge (while
// any remain for this thread) + one cvt float4-group. All waves issue cvt
// loads -> full BW; scatter latency hides under the stream.
__global__ __launch_bounds__(256)
void k_prep(const fvec4* __restrict__ H, half4* __restrict__ Hh, size_t n4,
            const unsigned long long* __restrict__ ei, const float* __restrict__ ew,
            const int* __restrict__ inv, int* __restrict__ cursor,
            unsigned* __restrict__ edges, int* __restrict__ ovfcnt,
            uint2* __restrict__ ovf, int B, int E, int N) {
    size_t tid0 = (size_t)blockIdx.x * 256 + threadIdx.x;
    size_t stride = (size_t)gridDim.x * 256;
    long long total = (long long)B * E;
    long long sIdx = (long long)tid0;

    for (size_t i = tid0; i < n4; i += stride) {
        if (sIdx < total) {
            int idx = (int)sIdx;
            unsigned long long pq = __builtin_nontemporal_load(&ei[idx]);
            int b = idx / E;
            int dst = inv[(int)(pq & 0xFFFFFFFFull)];
            int src = inv[(int)(pq >> 32)];
            float w = __builtin_nontemporal_load(&ew[idx]);
            _Float16 hw = (_Float16)w;
            unsigned short wb; __builtin_memcpy(&wb, &hw, 2);
            unsigned rec = (unsigned)(unsigned short)src | ((unsigned)wb << 16);
            size_t cidx = (size_t)b * N + dst;
            int pos = atomicAdd(&cursor[cidx], 1);
            if (pos < CAP) {
                __builtin_nontemporal_store(rec, &edges[cidx * CAP + pos]);
            } else {
                int op = atomicAdd(ovfcnt, 1);
                if (op < OVFCAP)
                    ovf[op] = make_uint2(((unsigned)b << 16) | (unsigned)dst, rec);
            }
            sIdx += (long long)stride;
        }
        fvec4 v = __builtin_nontemporal_load(&H[i]);
        half4 o;
        o.x = (_Float16)v.x; o.y = (_Float16)v.y;
        o.z = (_Float16)v.z; o.w = (_Float16)v.w;
        Hh[i] = o;   // cacheable: this IS the gather working set
    }
    // drain remaining scatter edges (only if scatter iters > cvt iters)
    for (; sIdx < total; sIdx += (long long)stride) {
        int idx = (int)sIdx;
        unsigned long long pq = __builtin_nontemporal_load(&ei[idx]);
        int b = idx / E;
        int dst = inv[(int)(pq & 0xFFFFFFFFull)];
        int src = inv[(int)(pq >> 32)];
        float w = __builtin_nontemporal_load(&ew[idx]);
        _Float16 hw = (_Float16)w;
        unsigned short wb; __builtin_memcpy(&wb, &hw, 2);
        unsigned rec = (unsigned)(unsigned short)src | ((unsigned)wb << 16);
        size_t cidx = (size_t)b * N + dst;
        int pos = atomicAdd(&cursor[cidx], 1);
        if (pos < CAP) {
            __builtin_nontemporal_store(rec, &edges[cidx * CAP + pos]);
        } else {
            int op = atomicAdd(ovfcnt, 1);
            if (op < OVFCAP)
                ovf[op] = make_uint2(((unsigned)b << 16) | (unsigned)dst, rec);
        }
    }
}

__device__ inline void fma4(fvec4& acc, float w, half4 h) {
    acc.x += w * (float)h.x; acc.y += w * (float)h.y;
    acc.z += w * (float)h.z; acc.w += w * (float)h.w;
}

// xpb > 0: XCD-partitioned flat grid. xcd = bi&7 owns batch b = xcd/xpb;
// group index k = (bi>>3)*xpb + (xcd%xpb).
__global__ __launch_bounds__(256)
void k_agg_gap(const _Float16* __restrict__ Hh, const int* __restrict__ cursor,
               const unsigned* __restrict__ edges, float* __restrict__ out,
               int B, int N, int xpb) {
    int lane = threadIdx.x & 63;
    int wid = threadIdx.x >> 6;
    int b, grp;
    if (xpb > 0) {
        int bi = blockIdx.x;
        int xcd = bi & 7;
        b = xcd / xpb;
        grp = (bi >> 3) * xpb + (xcd % xpb);
    } else {
        b = blockIdx.y;
        grp = blockIdx.x;
    }
    int node = grp * 4 + wid;
    if (node >= N) return;
    size_t sidx = (size_t)b * N + node;
    int deg = cursor[sidx];
    if (deg > CAP) deg = CAP;
    const unsigned* seg = edges + sidx * CAP;
    unsigned rec = 0;
    if (lane < deg) rec = __builtin_nontemporal_load(&seg[lane]);  // one 128B line
    const half4* Hb = (const half4*)(Hh + (size_t)b * N * ROW);
    fvec4 acc = {0.f, 0.f, 0.f, 0.f};
    int j = 0;
    for (; j + 8 <= deg; j += 8) {
        int sv[8]; float wv[8];
#pragma unroll
        for (int u = 0; u < 8; ++u) {
            unsigned r = __shfl(rec, j + u);
            sv[u] = (int)(r & 0xFFFFu);
            wv[u] = h2f_bits((unsigned short)(r >> 16));
        }
        half4 hv[8];
#pragma unroll
        for (int u = 0; u < 8; ++u) hv[u] = Hb[(size_t)sv[u] * 64 + lane];
#pragma unroll
        for (int u = 0; u < 8; ++u) fma4(acc, wv[u], hv[u]);
    }
    if (j + 4 <= deg) {
        int sv[4]; float wv[4];
#pragma unroll
        for (int u = 0; u < 4; ++u) {
            unsigned r = __shfl(rec, j + u);
            sv[u] = (int)(r & 0xFFFFu);
            wv[u] = h2f_bits((unsigned short)(r >> 16));
        }
        half4 hv[4];
#pragma unroll
        for (int u = 0; u < 4; ++u) hv[u] = Hb[(size_t)sv[u] * 64 + lane];
#pragma unroll
        for (int u = 0; u < 4; ++u) fma4(acc, wv[u], hv[u]);
        j += 4;
    }
    for (; j < deg; ++j) {
        unsigned r = __shfl(rec, j);
        half4 h = Hb[(size_t)(r & 0xFFFFu) * 64 + lane];
        fma4(acc, h2f_bits((unsigned short)(r >> 16)), h);
    }
    __builtin_nontemporal_store(acc, (fvec4*)out + (sidx * 64 + lane));
}

// Apply rare cap-overflow edges with fp32 atomics (runs after k_agg_gap).
__global__ __launch_bounds__(256)
void k_ovf(const _Float16* __restrict__ Hh, const int* __restrict__ ovfcnt,
           const uint2* __restrict__ ovf, float* __restrict__ out, int N) {
    int lane = threadIdx.x & 63;
    int wv = (blockIdx.x * 256 + (int)threadIdx.x) >> 6;
    int nw = gridDim.x * 4;
    int count = *ovfcnt;
    if (count > OVFCAP) count = OVFCAP;
    for (int i = wv; i < count; i += nw) {
        uint2 v = ovf[i];
        int b = (int)(v.x >> 16);
        int dst = (int)(v.x & 0xFFFFu);
        int src = (int)(v.y & 0xFFFFu);
        float w = h2f_bits((unsigned short)(v.y >> 16));
        half4 h = ((const half4*)(Hh + (size_t)b * N * ROW))[(size_t)src * 64 + lane];
        float* op = out + ((size_t)b * N + dst) * ROW + lane * 4;
        atomicAdd(op + 0, w * (float)h.x);
        atomicAdd(op + 1, w * (float)h.y);
        atomicAdd(op + 2, w * (float)h.z);
        atomicAdd(op + 3, w * (float)h.w);
    }
}

// ---- minimal-workspace fallback ----
__global__ void k_zero_f32(float* __restrict__ p, size_t n) {
    size_t i = (size_t)blockIdx.x * blockDim.x + threadIdx.x;
    if (i < n) p[i] = 0.f;
}

__global__ void k_atomic_agg(const float* __restrict__ H, const int* __restrict__ ei,
                             const float* __restrict__ ew, const int* __restrict__ inv,
                             float* __restrict__ out, int B, int E, int N) {
    int lane = threadIdx.x & 63;
    int widx = (blockIdx.x * blockDim.x + threadIdx.x) >> 6;
    int total = B * E;
    if (widx >= total) return;
    int b = widx / E;
    int d = ei[(size_t)widx * 2];
    int s = ei[(size_t)widx * 2 + 1];
    if (inv) { d = inv[d]; s = inv[s]; }
    float w = ew[widx];
    const float4* hp = (const float4*)(H + ((size_t)b * N + s) * ROW);
    float4 h = hp[lane];
    float* op = out + ((size_t)b * N + d) * ROW + lane * 4;
    atomicAdd(op + 0, w * h.x);
    atomicAdd(op + 1, w * h.y);
    atomicAdd(op + 2, w * h.z);
    atomicAdd(op + 3, w * h.w);
}

static inline size_t alignup(size_t x) { return (x + 255) & ~(size_t)255; }

extern "C" void kernel_launch(void* const* d_in, const int* in_sizes, int n_in,
                              void* d_out, int out_size, void* d_ws, size_t ws_size,
                              hipStream_t stream) {
    const float* H = (const float*)d_in[0];
    const int* ei = (const int*)d_in[1];
    const float* ew = (const float*)d_in[2];
    const int* nidx = (const int*)d_in[3];
    float* out = (float*)d_out;

    int N = in_sizes[3];                    // 50000
    int B = in_sizes[0] / (N * ROW);        // 4
    int E = in_sizes[2] / B;                // 800000
    int total = B * E;
    size_t nH = (size_t)B * N * ROW;
    char* w0 = (char*)d_ws;

    // ---- workspace layout: inv | cursor(B*N)+ovfcnt | ovf | segments | Hh ----
    size_t o_inv = 0;
    size_t o_cur = alignup(o_inv + (size_t)N * 4);
    size_t ncur = (size_t)B * N + 1;                      // cursors + ovfcnt
    size_t o_ovf = alignup(o_cur + ncur * 4);
    size_t o_seg = alignup(o_ovf + (size_t)OVFCAP * 8);
    size_t o_hh = alignup(o_seg + (size_t)B * N * CAP * 4);
    size_t req = o_hh + nH * 2;

    if (ws_size >= req && N <= 65535 && B <= 65535) {
        int* g_inv = (int*)(w0 + o_inv);
        int* g_cursor = (int*)(w0 + o_cur);
        int* g_ovfcnt = g_cursor + (size_t)B * N;
        uint2* g_ovf = (uint2*)(w0 + o_ovf);
        unsigned* g_edges = (unsigned*)(w0 + o_seg);
        _Float16* Hh = (_Float16*)(w0 + o_hh);

        int nz = (int)ncur;
        int ninit = max(N, nz);
        k_init<<<(ninit + 255) / 256, 256, 0, stream>>>(nidx, g_inv, g_cursor, nz, N);
        k_prep<<<2048, 256, 0, stream>>>(
            (const fvec4*)H, (half4*)Hh, nH / 4,
            (const unsigned long long*)ei, ew, g_inv, g_cursor, g_edges,
            g_ovfcnt, g_ovf, B, E, N);

        int groupsPerB = (N + 3) / 4;
        int xpb = (B > 0 && 8 % B == 0) ? 8 / B : 0;
        bool can_swz = xpb > 0 && (groupsPerB % xpb) == 0 &&
                       (((size_t)groupsPerB * B) % 8) == 0;
        if (can_swz) {
            k_agg_gap<<<groupsPerB * B, 256, 0, stream>>>(
                Hh, g_cursor, g_edges, out, B, N, xpb);
        } else {
            dim3 ag(groupsPerB, B);
            k_agg_gap<<<ag, 256, 0, stream>>>(Hh, g_cursor, g_edges, out, B, N, 0);
        }
        k_ovf<<<256, 256, 0, stream>>>(Hh, g_ovfcnt, g_ovf, out, N);
        return;
    }

    // ---- fallback: per-edge atomics ----
    int* finv = nullptr;
    if (ws_size >= (size_t)N * sizeof(int)) {
        finv = (int*)d_ws;
        k_init<<<(N + 255) / 256, 256, 0, stream>>>(nidx, finv, finv, 0, N);
    }
    size_t on = (size_t)out_size;
    k_zero_f32<<<(int)((on + 255) / 256), 256, 0, stream>>>(out, on);
    int blocks = (total * 64 + 255) / 256;
    k_atomic_agg<<<blocks, 256, 0, stream>>>(H, ei, ew, finv, out, B, E, N);
}